// Round 20
// baseline (183.354 us; speedup 1.0000x reference)
//
#include <hip/hip_runtime.h>
#include <hip/hip_bf16.h>
#include <stdint.h>
#include <math.h>

#define B_ 4
#define T_ 2048
#define E_ 1024
#define H_ 16
#define D_ 64

typedef __attribute__((ext_vector_type(8))) short short8;
typedef __attribute__((ext_vector_type(4))) short short4v;
typedef __attribute__((ext_vector_type(4))) float f32x4;

#define MFMA_BF16(a, b, c) __builtin_amdgcn_mfma_f32_16x16x32_bf16((a), (b), (c), 0, 0, 0)

__device__ __forceinline__ unsigned short f2bf(float f) {
  union { float f; unsigned u; } v; v.f = f;
  unsigned r = v.u + 0x7FFFu + ((v.u >> 16) & 1u);  // RNE
  return (unsigned short)(r >> 16);
}

#define GLOAD_LDS16(g, l)                                                        \
  __builtin_amdgcn_global_load_lds((const __attribute__((address_space(1))) void*)(g), \
                                   (__attribute__((address_space(3))) void*)(l), 16, 0, 0)

// ---------------- fp32 -> bf16 convert: x + 4 weights in ONE launch ----------
__global__ __launch_bounds__(256) void cvt_all(const float* __restrict__ x,
                                               const float* __restrict__ w0,
                                               const float* __restrict__ w1,
                                               const float* __restrict__ w2,
                                               const float* __restrict__ w3,
                                               unsigned short* __restrict__ xb,
                                               unsigned short* __restrict__ wb) {
  const int NX8 = 1048576;  // XE/8
  int i = blockIdx.x * blockDim.x + threadIdx.x;
  const float* src;
  unsigned short* dst;
  size_t off;
  if (i < NX8) {
    src = x; dst = xb; off = (size_t)i * 8;
  } else {
    int j = i - NX8;
    int which = j >> 17;             // WE/8 = 2^17
    int o = j & 131071;
    src = (which == 0) ? w0 : (which == 1) ? w1 : (which == 2) ? w2 : w3;
    dst = wb + ((size_t)which << 20);
    off = (size_t)o * 8;
  }
  const float4* p = (const float4*)(src + off);
  float4 a = p[0], b = p[1];
  short8 r;
  r[0] = (short)f2bf(a.x); r[1] = (short)f2bf(a.y);
  r[2] = (short)f2bf(a.z); r[3] = (short)f2bf(a.w);
  r[4] = (short)f2bf(b.x); r[5] = (short)f2bf(b.y);
  r[6] = (short)f2bf(b.z); r[7] = (short)f2bf(b.w);
  *(short8*)(dst + off) = r;
}

// =============== 128x256 2-phase pipelined GEMM template (r18, proven) =======
#define GEMM2_BODY(A_PTR, B_PTR)                                                  \
  const int K = E_;                                                               \
  const int NT = 16;                                                              \
  const int tid = threadIdx.x;                                                    \
  const int wid = tid >> 6;                                                       \
  const int lane = tid & 63;                                                      \
  const int lr = lane & 15;                                                       \
  const int lk = lane >> 4;                                                       \
  const int wm = wid >> 2, wn = wid & 3;                                          \
  const int srow = lane >> 3;                                                     \
  const int scol = ((lane & 7) ^ srow) * 8;                                       \
  const int rswz = (lr & 7) << 4;                                                 \
  const int kofs0 = (lk * 16) ^ rswz;                                             \
  const int kofs1 = (64 + lk * 16) ^ rswz;                                        \
  f32x4 acc[4][4] = {};                                                           \
  short8 af[4][2], bf0[2][2], bf1[2][2];                                          \
  auto stageA = [&](int tau) {                                                    \
    char* dst = lds + (tau & 1) * 49152 + wid * 1024;                             \
    const unsigned short* src = (A_PTR) + (size_t)(m0 + wid * 8 + srow) * K +     \
                                tau * 64 + scol;                                  \
    GLOAD_LDS16(src, dst);                                                        \
    GLOAD_LDS16(src + (size_t)64 * K, dst + 8192);                                \
  };                                                                              \
  auto stageB = [&](int tau) {                                                    \
    char* dst = lds + (tau & 1) * 49152 + 16384 + wid * 1024;                     \
    const unsigned short* src = (B_PTR) + (size_t)(n0 + wid * 8 + srow) * K +     \
                                tau * 64 + scol;                                  \
    GLOAD_LDS16(src, dst);                                                        \
    GLOAD_LDS16(src + (size_t)64 * K, dst + 8192);                                \
    GLOAD_LDS16(src + (size_t)128 * K, dst + 16384);                              \
    GLOAD_LDS16(src + (size_t)192 * K, dst + 24576);                              \
  };                                                                              \
  stageB(0); stageA(0); stageB(1);                                                \
  asm volatile("s_waitcnt vmcnt(4)" ::: "memory");                                \
  __builtin_amdgcn_s_barrier();                                                   \
  for (int t = 0; t < NT; ++t) {                                                  \
    char* bufA = lds + (t & 1) * 49152;                                           \
    char* bufB = bufA + 16384;                                                    \
    _Pragma("unroll")                                                             \
    for (int i = 0; i < 4; ++i) {                                                 \
      int row = wm * 64 + i * 16 + lr;                                            \
      af[i][0] = *(const short8*)(bufA + row * 128 + kofs0);                      \
      af[i][1] = *(const short8*)(bufA + row * 128 + kofs1);                      \
    }                                                                             \
    _Pragma("unroll")                                                             \
    for (int i = 0; i < 2; ++i) {                                                 \
      int row0 = wn * 64 + i * 16 + lr;                                           \
      int row1 = wn * 64 + (2 + i) * 16 + lr;                                     \
      bf0[i][0] = *(const short8*)(bufB + row0 * 128 + kofs0);                    \
      bf0[i][1] = *(const short8*)(bufB + row0 * 128 + kofs1);                    \
      bf1[i][0] = *(const short8*)(bufB + row1 * 128 + kofs0);                    \
      bf1[i][1] = *(const short8*)(bufB + row1 * 128 + kofs1);                    \
    }                                                                             \
    if (t + 1 < NT) stageA(t + 1);                                                \
    __builtin_amdgcn_s_barrier();                                                 \
    asm volatile("s_waitcnt lgkmcnt(0)" ::: "memory");                            \
    __builtin_amdgcn_sched_barrier(0);                                            \
    __builtin_amdgcn_s_setprio(1);                                                \
    _Pragma("unroll")                                                             \
    for (int i = 0; i < 4; ++i)                                                   \
      _Pragma("unroll")                                                           \
      for (int jn = 0; jn < 2; ++jn) {                                            \
        acc[i][jn] = MFMA_BF16(af[i][0], bf0[jn][0], acc[i][jn]);                 \
        acc[i][jn] = MFMA_BF16(af[i][1], bf0[jn][1], acc[i][jn]);                 \
      }                                                                           \
    __builtin_amdgcn_s_setprio(0);                                                \
    __builtin_amdgcn_s_barrier();                                                 \
    if (t + 2 < NT) stageB(t + 2);                                                \
    __builtin_amdgcn_s_setprio(1);                                                \
    _Pragma("unroll")                                                             \
    for (int i = 0; i < 4; ++i)                                                   \
      _Pragma("unroll")                                                           \
      for (int jn = 0; jn < 2; ++jn) {                                            \
        acc[i][2 + jn] = MFMA_BF16(af[i][0], bf1[jn][0], acc[i][2 + jn]);         \
        acc[i][2 + jn] = MFMA_BF16(af[i][1], bf1[jn][1], acc[i][2 + jn]);         \
      }                                                                           \
    __builtin_amdgcn_s_setprio(0);                                                \
    if (t < NT - 2) asm volatile("s_waitcnt vmcnt(4)" ::: "memory");              \
    else            asm volatile("s_waitcnt vmcnt(0)" ::: "memory");              \
    __builtin_amdgcn_s_barrier();                                                 \
  }

// ---------------- QKV GEMM (768 blocks = 3 exact rounds at 1 blk/CU) ---------
__global__ __launch_bounds__(512) void gemm_qkv2(const unsigned short* __restrict__ A,
                                                 const unsigned short* __restrict__ Wq,
                                                 const unsigned short* __restrict__ Wk,
                                                 const unsigned short* __restrict__ Wv,
                                                 unsigned short* __restrict__ Qo,
                                                 unsigned short* __restrict__ Ko,
                                                 unsigned short* __restrict__ Vo) {
  __shared__ __align__(16) char lds[98304];
  const int bid = blockIdx.x;
  const int xcd = bid & 7;
  const int p = bid >> 3;               // 0..95
  const int m0 = (xcd * 8 + (p & 7)) * 128;
  const int j = p >> 3;                 // 0..11
  const int n0 = (j & 3) * 256;
  const int sel = j >> 2;
  const unsigned short* Bm = (sel == 0) ? Wq : (sel == 1) ? Wk : Wv;

  GEMM2_BODY(A, Bm)

  unsigned short* outp = (sel == 0) ? Qo : (sel == 1) ? Ko : Vo;
#pragma unroll
  for (int mi = 0; mi < 4; ++mi)
#pragma unroll
    for (int ni = 0; ni < 4; ++ni) {
      int row0 = m0 + wm * 64 + mi * 16 + lk * 4;
      int col = n0 + wn * 64 + ni * 16 + lr;
      int b = row0 >> 11, t0 = row0 & (T_ - 1), h = col >> 6, d = col & (D_ - 1);
      if (sel == 2) {
        short4v vv;
#pragma unroll
        for (int r = 0; r < 4; ++r) vv[r] = (short)f2bf(acc[mi][ni][r]);
        *(short4v*)&outp[(((size_t)(b * H_ + h)) * D_ + d) * T_ + t0] = vv;  // [BH][D][T]
      } else {
#pragma unroll
        for (int r = 0; r < 4; ++r)
          outp[(((size_t)(b * H_ + h)) * T_ + t0 + r) * D_ + d] = f2bf(acc[mi][ni][r]);
      }
    }
}

// ---------------- out-proj GEMM (256 blocks = exactly 1/CU) ------------------
__global__ __launch_bounds__(512) void gemm_out2(const unsigned short* __restrict__ A,
                                                 const unsigned short* __restrict__ Wout,
                                                 float* __restrict__ outp,
                                                 const float* __restrict__ bias) {
  __shared__ __align__(16) char lds[98304];
  const int bid = blockIdx.x;
  const int xcd = bid & 7;
  const int p = bid >> 3;               // 0..31
  const int m0 = (xcd * 8 + (p & 7)) * 128;
  const int n0 = (p >> 3) * 256;

  GEMM2_BODY(A, Wout)

#pragma unroll
  for (int mi = 0; mi < 4; ++mi)
#pragma unroll
    for (int ni = 0; ni < 4; ++ni) {
      int row0 = m0 + wm * 64 + mi * 16 + lk * 4;
      int col = n0 + wn * 64 + ni * 16 + lr;
      float bv = bias[col];
#pragma unroll
      for (int r = 0; r < 4; ++r)
        outp[(size_t)(row0 + r) * E_ + col] = acc[mi][ni][r] + bv;
    }
}

// ---------------- fused causal flash attention (8-wave LDS-staged) -----------
// 512 blocks x 512 thr, 2 blocks/CU ALL resident. Heavy/light CO-RESIDENCY
// pairing: block b (b<256) takes Qb in {7..4}, block b+256 the complement in
// {0..3} — linear dispatch puts b and b+256 on the SAME CU, so every CU owns
// exactly 36 tiles and all finish together (r19: 21% occ was this imbalance).
__global__ __launch_bounds__(512) void attn_fused8(const unsigned short* __restrict__ Q,
                                                   const unsigned short* __restrict__ K,
                                                   const unsigned short* __restrict__ VT,
                                                   unsigned short* __restrict__ ctx) {
  __shared__ __align__(16) char kvb[2][16384];  // [buf][K 8K | V 8K]
  __shared__ __align__(16) char Pl[8][4608];    // per-wave P: 32 x 144B
  const int tid = threadIdx.x;
  const int wid = tid >> 6;
  const int lane = tid & 63;
  const int lr = lane & 15;
  const int lk = lane >> 4;

  // pairing map: b<256 -> Qb=7-j (heavy); b>=256 -> Qb=j (light); same head.
  const int bid = blockIdx.x;
  const int half = bid >> 8;
  const int b2 = bid & 255;
  const int xcd = b2 & 7;
  const int p = b2 >> 3;             // 0..31
  const int bh = xcd * 8 + (p & 7);
  const int j = p >> 3;              // 0..3
  const int Qb = half ? j : (7 - j);

  const unsigned short* Qh = Q + (size_t)bh * T_ * D_;
  const unsigned short* Kh = K + (size_t)bh * T_ * D_;
  const unsigned short* Vh = VT + (size_t)bh * T_ * D_;  // [D][T]
  char* Pb = Pl[wid];

  const int q0w = Qb * 256 + wid * 32;
  const int diag = q0w >> 6;         // wave's diagonal kv-tile
  const int ql0 = (wid & 1) * 32;    // q-local base within diag tile
  const int NTb = 4 * Qb + 4;        // block trip count

  const float SC = 0.125f * 1.44269504089f;  // 1/sqrt(D) * log2(e)

  // staging: thread stages one 16B chunk of K and one of V per tile
  const int srow = tid >> 3;                       // 0..63
  const int scol = ((tid & 7) ^ (srow & 7)) * 8;   // pre-swizzled col (elems)
  const int rswz = (lr & 7) << 4;                  // read-side XOR (bytes)

  auto stage = [&](int t) {
    char* dst = kvb[t & 1] + tid * 16;
    GLOAD_LDS16(Kh + (size_t)(t * 64 + srow) * D_ + scol, dst);
    GLOAD_LDS16(Vh + (size_t)srow * T_ + t * 64 + scol, dst + 8192);
  };

  short8 vones;
#pragma unroll
  for (int jj = 0; jj < 8; ++jj) vones[jj] = (short)0x3F80;  // bf16 1.0

  // Q as B-operand: col=q=lr, k=d
  short8 qf[2][2];
#pragma unroll
  for (int a = 0; a < 2; ++a)
#pragma unroll
    for (int kb = 0; kb < 2; ++kb)
      qf[a][kb] = *(const short8*)&Qh[(size_t)(q0w + a * 16 + lr) * D_ + kb * 32 + lk * 8];

  f32x4 o[2][4] = {};
  f32x4 lsum[2] = {};
  float mrun[2] = {-1e30f, -1e30f};

  stage(0);
  asm volatile("s_waitcnt vmcnt(0)" ::: "memory");
  __builtin_amdgcn_s_barrier();

  for (int t = 0; t < NTb; ++t) {
    if (t + 1 < NTb) stage(t + 1);  // other parity buffer: safe vs tile-t reads

    if (t <= diag) {
      char* kb_ = kvb[t & 1];
      char* vb_ = kvb[t & 1] + 8192;

      // K fragments from LDS (2-way conflict = free)
      short8 kf[2][4];
#pragma unroll
      for (int kb = 0; kb < 2; ++kb)
#pragma unroll
        for (int n = 0; n < 4; ++n)
          kf[kb][n] = *(const short8*)(kb_ + (n * 16 + lr) * 128 + ((kb * 64 + lk * 16) ^ rswz));

      // S^T = K Q^T
      f32x4 st[2][4] = {};
#pragma unroll
      for (int kb = 0; kb < 2; ++kb)
#pragma unroll
        for (int a = 0; a < 2; ++a)
#pragma unroll
          for (int n = 0; n < 4; ++n)
            st[a][n] = MFMA_BF16(kf[kb][n], qf[a][kb], st[a][n]);

      if (t == diag) {  // causal mask
#pragma unroll
        for (int a = 0; a < 2; ++a)
#pragma unroll
          for (int n = 0; n < 4; ++n)
#pragma unroll
            for (int r = 0; r < 4; ++r)
              if (n * 16 + lk * 4 + r > ql0 + a * 16 + lr) st[a][n][r] = -3e38f;
      }

      // row max (in-lane tree + 2 shuffles)
      float pm[2];
#pragma unroll
      for (int a = 0; a < 2; ++a) {
        float m0 = fmaxf(fmaxf(st[a][0][0], st[a][1][0]), fmaxf(st[a][2][0], st[a][3][0]));
        float m1 = fmaxf(fmaxf(st[a][0][1], st[a][1][1]), fmaxf(st[a][2][1], st[a][3][1]));
        float m2 = fmaxf(fmaxf(st[a][0][2], st[a][1][2]), fmaxf(st[a][2][2], st[a][3][2]));
        float m3 = fmaxf(fmaxf(st[a][0][3], st[a][1][3]), fmaxf(st[a][2][3], st[a][3][3]));
        float mx = fmaxf(fmaxf(m0, m1), fmaxf(m2, m3));
        mx = fmaxf(mx, __shfl_xor(mx, 16));
        mx = fmaxf(mx, __shfl_xor(mx, 32));
        pm[a] = mx * SC;
      }
      float need = fmaxf(pm[0] - mrun[0], pm[1] - mrun[1]);

      if (__any(need > 8.f)) {  // defer-max rescale (rare)
#pragma unroll
        for (int a = 0; a < 2; ++a) {
          float mnew = fmaxf(mrun[a], pm[a]);
          float sc = exp2f(mrun[a] - mnew);
          mrun[a] = mnew;
#pragma unroll
          for (int r = 0; r < 4; ++r) {
            float sco = __shfl(sc, (lane & 48) | (lk * 4 + r));
            lsum[a][r] *= sco;
#pragma unroll
            for (int nd = 0; nd < 4; ++nd) o[a][nd][r] *= sco;
          }
        }
      }

      // P = exp2(S*SC - m), packed bf16x4 -> per-wave LDS
#pragma unroll
      for (int a = 0; a < 2; ++a)
#pragma unroll
        for (int n = 0; n < 4; ++n) {
          float2 p01, p23;
          p01.x = exp2f(fmaf(st[a][n][0], SC, -mrun[a]));
          p01.y = exp2f(fmaf(st[a][n][1], SC, -mrun[a]));
          p23.x = exp2f(fmaf(st[a][n][2], SC, -mrun[a]));
          p23.y = exp2f(fmaf(st[a][n][3], SC, -mrun[a]));
          __hip_bfloat162 b01 = __float22bfloat162_rn(p01);
          __hip_bfloat162 b23 = __float22bfloat162_rn(p23);
          uint2 w;
          w.x = *(unsigned*)&b01;
          w.y = *(unsigned*)&b23;
          *(uint2*)(Pb + (a * 16 + lr) * 144 + n * 32 + lk * 8) = w;
        }

      // V fragments from LDS + in-tile PV (compiler waits P write->read)
      short8 vf[2][4];
#pragma unroll
      for (int kb = 0; kb < 2; ++kb)
#pragma unroll
        for (int nd = 0; nd < 4; ++nd)
          vf[kb][nd] = *(const short8*)(vb_ + (nd * 16 + lr) * 128 + ((kb * 64 + lk * 16) ^ rswz));
#pragma unroll
      for (int kb = 0; kb < 2; ++kb) {
        short8 pf0 = *(const short8*)(Pb + (0 + lr) * 144 + kb * 64 + lk * 16);
        short8 pf1 = *(const short8*)(Pb + (16 + lr) * 144 + kb * 64 + lk * 16);
#pragma unroll
        for (int nd = 0; nd < 4; ++nd) {
          o[0][nd] = MFMA_BF16(pf0, vf[kb][nd], o[0][nd]);
          o[1][nd] = MFMA_BF16(pf1, vf[kb][nd], o[1][nd]);
        }
        lsum[0] = MFMA_BF16(pf0, vones, lsum[0]);
        lsum[1] = MFMA_BF16(pf1, vones, lsum[1]);
      }
    }

    asm volatile("s_waitcnt vmcnt(0)" ::: "memory");  // stage(t+1) landed
    __builtin_amdgcn_s_barrier();
  }

  const int b = bh >> 4, h2 = bh & 15;
#pragma unroll
  for (int a = 0; a < 2; ++a)
#pragma unroll
    for (int r = 0; r < 4; ++r) {
      float inv = 1.0f / lsum[a][r];
      int tq = q0w + a * 16 + lk * 4 + r;
#pragma unroll
      for (int nd = 0; nd < 4; ++nd)
        ctx[((size_t)b * T_ + tq) * E_ + h2 * D_ + nd * 16 + lr] = f2bf(o[a][nd][r] * inv);
    }
}

// ---------------- launcher ----------------
extern "C" void kernel_launch(void* const* d_in, const int* in_sizes, int n_in,
                              void* d_out, int out_size, void* d_ws, size_t ws_size,
                              hipStream_t stream) {
  const float* x    = (const float*)d_in[0];
  const float* Wq   = (const float*)d_in[1];
  const float* Wk   = (const float*)d_in[2];
  const float* Wv   = (const float*)d_in[3];
  const float* Wout = (const float*)d_in[4];
  const float* bout = (const float*)d_in[5];
  float* out = (float*)d_out;

  const size_t MT = (size_t)B_ * T_;      // 8192
  const size_t XE = MT * E_;              // 8,388,608
  const size_t WE = (size_t)E_ * E_;      // 1,048,576

  size_t need = (XE * 5 + WE * 4) * sizeof(unsigned short);
  if (ws_size < need) return;

  unsigned short* xb  = (unsigned short*)d_ws;
  unsigned short* wqb = xb + XE;
  unsigned short* wkb = wqb + WE;
  unsigned short* wvb = wkb + WE;
  unsigned short* wob = wvb + WE;
  unsigned short* Qb  = wob + WE;
  unsigned short* Kb  = Qb + XE;
  unsigned short* VTb = Kb + XE;
  unsigned short* ctx = VTb + XE;

  cvt_all<<<6144, 256, 0, stream>>>(x, Wq, Wk, Wv, Wout, xb, wqb);

  gemm_qkv2<<<768, 512, 0, stream>>>(xb, wqb, wkb, wvb, Qb, Kb, VTb);

  attn_fused8<<<512, 512, 0, stream>>>(Qb, Kb, VTb, ctx);

  gemm_out2<<<256, 512, 0, stream>>>(ctx, wob, out, bout);
}

// Round 21
// 169.094 us; speedup vs baseline: 1.0843x; 1.0843x over previous
//
#include <hip/hip_runtime.h>
#include <hip/hip_bf16.h>
#include <stdint.h>
#include <math.h>

#define B_ 4
#define T_ 2048
#define E_ 1024
#define H_ 16
#define D_ 64

typedef __attribute__((ext_vector_type(8))) short short8;
typedef __attribute__((ext_vector_type(4))) short short4v;
typedef __attribute__((ext_vector_type(4))) float f32x4;

#define MFMA_BF16(a, b, c) __builtin_amdgcn_mfma_f32_16x16x32_bf16((a), (b), (c), 0, 0, 0)

__device__ __forceinline__ unsigned short f2bf(float f) {
  union { float f; unsigned u; } v; v.f = f;
  unsigned r = v.u + 0x7FFFu + ((v.u >> 16) & 1u);  // RNE
  return (unsigned short)(r >> 16);
}

#define GLOAD_LDS16(g, l)                                                        \
  __builtin_amdgcn_global_load_lds((const __attribute__((address_space(1))) void*)(g), \
                                   (__attribute__((address_space(3))) void*)(l), 16, 0, 0)

// ---------------- fp32 -> bf16 convert: x + 4 weights in ONE launch ----------
__global__ __launch_bounds__(256) void cvt_all(const float* __restrict__ x,
                                               const float* __restrict__ w0,
                                               const float* __restrict__ w1,
                                               const float* __restrict__ w2,
                                               const float* __restrict__ w3,
                                               unsigned short* __restrict__ xb,
                                               unsigned short* __restrict__ wb) {
  const int NX8 = 1048576;  // XE/8
  int i = blockIdx.x * blockDim.x + threadIdx.x;
  const float* src;
  unsigned short* dst;
  size_t off;
  if (i < NX8) {
    src = x; dst = xb; off = (size_t)i * 8;
  } else {
    int j = i - NX8;
    int which = j >> 17;             // WE/8 = 2^17
    int o = j & 131071;
    src = (which == 0) ? w0 : (which == 1) ? w1 : (which == 2) ? w2 : w3;
    dst = wb + ((size_t)which << 20);
    off = (size_t)o * 8;
  }
  const float4* p = (const float4*)(src + off);
  float4 a = p[0], b = p[1];
  short8 r;
  r[0] = (short)f2bf(a.x); r[1] = (short)f2bf(a.y);
  r[2] = (short)f2bf(a.z); r[3] = (short)f2bf(a.w);
  r[4] = (short)f2bf(b.x); r[5] = (short)f2bf(b.y);
  r[6] = (short)f2bf(b.z); r[7] = (short)f2bf(b.w);
  *(short8*)(dst + off) = r;
}

// =============== 128x256 2-phase pipelined GEMM template (r18, proven) =======
#define GEMM2_BODY(A_PTR, B_PTR)                                                  \
  const int K = E_;                                                               \
  const int NT = 16;                                                              \
  const int tid = threadIdx.x;                                                    \
  const int wid = tid >> 6;                                                       \
  const int lane = tid & 63;                                                      \
  const int lr = lane & 15;                                                       \
  const int lk = lane >> 4;                                                       \
  const int wm = wid >> 2, wn = wid & 3;                                          \
  const int srow = lane >> 3;                                                     \
  const int scol = ((lane & 7) ^ srow) * 8;                                       \
  const int rswz = (lr & 7) << 4;                                                 \
  const int kofs0 = (lk * 16) ^ rswz;                                             \
  const int kofs1 = (64 + lk * 16) ^ rswz;                                        \
  f32x4 acc[4][4] = {};                                                           \
  short8 af[4][2], bf0[2][2], bf1[2][2];                                          \
  auto stageA = [&](int tau) {                                                    \
    char* dst = lds + (tau & 1) * 49152 + wid * 1024;                             \
    const unsigned short* src = (A_PTR) + (size_t)(m0 + wid * 8 + srow) * K +     \
                                tau * 64 + scol;                                  \
    GLOAD_LDS16(src, dst);                                                        \
    GLOAD_LDS16(src + (size_t)64 * K, dst + 8192);                                \
  };                                                                              \
  auto stageB = [&](int tau) {                                                    \
    char* dst = lds + (tau & 1) * 49152 + 16384 + wid * 1024;                     \
    const unsigned short* src = (B_PTR) + (size_t)(n0 + wid * 8 + srow) * K +     \
                                tau * 64 + scol;                                  \
    GLOAD_LDS16(src, dst);                                                        \
    GLOAD_LDS16(src + (size_t)64 * K, dst + 8192);                                \
    GLOAD_LDS16(src + (size_t)128 * K, dst + 16384);                              \
    GLOAD_LDS16(src + (size_t)192 * K, dst + 24576);                              \
  };                                                                              \
  stageB(0); stageA(0); stageB(1);                                                \
  asm volatile("s_waitcnt vmcnt(4)" ::: "memory");                                \
  __builtin_amdgcn_s_barrier();                                                   \
  for (int t = 0; t < NT; ++t) {                                                  \
    char* bufA = lds + (t & 1) * 49152;                                           \
    char* bufB = bufA + 16384;                                                    \
    _Pragma("unroll")                                                             \
    for (int i = 0; i < 4; ++i) {                                                 \
      int row = wm * 64 + i * 16 + lr;                                            \
      af[i][0] = *(const short8*)(bufA + row * 128 + kofs0);                      \
      af[i][1] = *(const short8*)(bufA + row * 128 + kofs1);                      \
    }                                                                             \
    _Pragma("unroll")                                                             \
    for (int i = 0; i < 2; ++i) {                                                 \
      int row0 = wn * 64 + i * 16 + lr;                                           \
      int row1 = wn * 64 + (2 + i) * 16 + lr;                                     \
      bf0[i][0] = *(const short8*)(bufB + row0 * 128 + kofs0);                    \
      bf0[i][1] = *(const short8*)(bufB + row0 * 128 + kofs1);                    \
      bf1[i][0] = *(const short8*)(bufB + row1 * 128 + kofs0);                    \
      bf1[i][1] = *(const short8*)(bufB + row1 * 128 + kofs1);                    \
    }                                                                             \
    if (t + 1 < NT) stageA(t + 1);                                                \
    __builtin_amdgcn_s_barrier();                                                 \
    asm volatile("s_waitcnt lgkmcnt(0)" ::: "memory");                            \
    __builtin_amdgcn_sched_barrier(0);                                            \
    __builtin_amdgcn_s_setprio(1);                                                \
    _Pragma("unroll")                                                             \
    for (int i = 0; i < 4; ++i)                                                   \
      _Pragma("unroll")                                                           \
      for (int jn = 0; jn < 2; ++jn) {                                            \
        acc[i][jn] = MFMA_BF16(af[i][0], bf0[jn][0], acc[i][jn]);                 \
        acc[i][jn] = MFMA_BF16(af[i][1], bf0[jn][1], acc[i][jn]);                 \
      }                                                                           \
    __builtin_amdgcn_s_setprio(0);                                                \
    __builtin_amdgcn_s_barrier();                                                 \
    if (t + 2 < NT) stageB(t + 2);                                                \
    __builtin_amdgcn_s_setprio(1);                                                \
    _Pragma("unroll")                                                             \
    for (int i = 0; i < 4; ++i)                                                   \
      _Pragma("unroll")                                                           \
      for (int jn = 0; jn < 2; ++jn) {                                            \
        acc[i][2 + jn] = MFMA_BF16(af[i][0], bf1[jn][0], acc[i][2 + jn]);         \
        acc[i][2 + jn] = MFMA_BF16(af[i][1], bf1[jn][1], acc[i][2 + jn]);         \
      }                                                                           \
    __builtin_amdgcn_s_setprio(0);                                                \
    if (t < NT - 2) asm volatile("s_waitcnt vmcnt(4)" ::: "memory");              \
    else            asm volatile("s_waitcnt vmcnt(0)" ::: "memory");              \
    __builtin_amdgcn_s_barrier();                                                 \
  }

// ---------------- QKV GEMM (768 blocks = 3 exact rounds at 1 blk/CU) ---------
__global__ __launch_bounds__(512) void gemm_qkv2(const unsigned short* __restrict__ A,
                                                 const unsigned short* __restrict__ Wq,
                                                 const unsigned short* __restrict__ Wk,
                                                 const unsigned short* __restrict__ Wv,
                                                 unsigned short* __restrict__ Qo,
                                                 unsigned short* __restrict__ Ko,
                                                 unsigned short* __restrict__ Vo) {
  __shared__ __align__(16) char lds[98304];
  const int bid = blockIdx.x;
  const int xcd = bid & 7;
  const int p = bid >> 3;               // 0..95
  const int m0 = (xcd * 8 + (p & 7)) * 128;
  const int j = p >> 3;                 // 0..11
  const int n0 = (j & 3) * 256;
  const int sel = j >> 2;
  const unsigned short* Bm = (sel == 0) ? Wq : (sel == 1) ? Wk : Wv;

  GEMM2_BODY(A, Bm)

  unsigned short* outp = (sel == 0) ? Qo : (sel == 1) ? Ko : Vo;
#pragma unroll
  for (int mi = 0; mi < 4; ++mi)
#pragma unroll
    for (int ni = 0; ni < 4; ++ni) {
      int row0 = m0 + wm * 64 + mi * 16 + lk * 4;
      int col = n0 + wn * 64 + ni * 16 + lr;
      int b = row0 >> 11, t0 = row0 & (T_ - 1), h = col >> 6, d = col & (D_ - 1);
      if (sel == 2) {
        short4v vv;
#pragma unroll
        for (int r = 0; r < 4; ++r) vv[r] = (short)f2bf(acc[mi][ni][r]);
        *(short4v*)&outp[(((size_t)(b * H_ + h)) * D_ + d) * T_ + t0] = vv;  // [BH][D][T]
      } else {
#pragma unroll
        for (int r = 0; r < 4; ++r)
          outp[(((size_t)(b * H_ + h)) * T_ + t0 + r) * D_ + d] = f2bf(acc[mi][ni][r]);
      }
    }
}

// ---------------- out-proj GEMM (256 blocks = exactly 1/CU) ------------------
__global__ __launch_bounds__(512) void gemm_out2(const unsigned short* __restrict__ A,
                                                 const unsigned short* __restrict__ Wout,
                                                 float* __restrict__ outp,
                                                 const float* __restrict__ bias) {
  __shared__ __align__(16) char lds[98304];
  const int bid = blockIdx.x;
  const int xcd = bid & 7;
  const int p = bid >> 3;               // 0..31
  const int m0 = (xcd * 8 + (p & 7)) * 128;
  const int n0 = (p >> 3) * 256;

  GEMM2_BODY(A, Wout)

#pragma unroll
  for (int mi = 0; mi < 4; ++mi)
#pragma unroll
    for (int ni = 0; ni < 4; ++ni) {
      int row0 = m0 + wm * 64 + mi * 16 + lk * 4;
      int col = n0 + wn * 64 + ni * 16 + lr;
      float bv = bias[col];
#pragma unroll
      for (int r = 0; r < 4; ++r)
        outp[(size_t)(row0 + r) * E_ + col] = acc[mi][ni][r] + bv;
    }
}

// ---------------- fused causal flash attention (8-wave, intrinsic pairing) ---
// 256 blocks x 512 thr = exactly 1 block/CU, ALL resident. Block g of head bh
// runs q-block (7-g) THEN g sequentially: 36 kv-tiles per block EXACTLY —
// balance is intrinsic, no dispatch-placement assumptions (r20 lesson).
// Per pass: r19's 8-wave LDS-staged body (double-buffered K/V, GEMM-proven
// swizzle, in-tile PV, per-wave P round-trip).
__global__ __launch_bounds__(512) void attn_fused8(const unsigned short* __restrict__ Q,
                                                   const unsigned short* __restrict__ K,
                                                   const unsigned short* __restrict__ VT,
                                                   unsigned short* __restrict__ ctx) {
  __shared__ __align__(16) char kvb[2][16384];  // [buf][K 8K | V 8K]
  __shared__ __align__(16) char Pl[8][4608];    // per-wave P: 32 x 144B
  const int tid = threadIdx.x;
  const int wid = tid >> 6;
  const int lane = tid & 63;
  const int lr = lane & 15;
  const int lk = lane >> 4;

  // 256 = 8 xcd x 8 heads x 4 pair-ids
  const int bid = blockIdx.x;
  const int xcd = bid & 7;
  const int p = bid >> 3;            // 0..31
  const int bh = xcd * 8 + (p & 7);
  const int g = p >> 3;              // 0..3

  const unsigned short* Qh = Q + (size_t)bh * T_ * D_;
  const unsigned short* Kh = K + (size_t)bh * T_ * D_;
  const unsigned short* Vh = VT + (size_t)bh * T_ * D_;  // [D][T]
  char* Pb = Pl[wid];

  const float SC = 0.125f * 1.44269504089f;  // 1/sqrt(D) * log2(e)

  // staging: thread stages one 16B chunk of K and one of V per tile
  const int srow = tid >> 3;                       // 0..63
  const int scol = ((tid & 7) ^ (srow & 7)) * 8;   // pre-swizzled col (elems)
  const int rswz = (lr & 7) << 4;                  // read-side XOR (bytes)

  auto stage = [&](int t) {
    char* dst = kvb[t & 1] + tid * 16;
    GLOAD_LDS16(Kh + (size_t)(t * 64 + srow) * D_ + scol, dst);
    GLOAD_LDS16(Vh + (size_t)srow * T_ + t * 64 + scol, dst + 8192);
  };

  short8 vones;
#pragma unroll
  for (int jj = 0; jj < 8; ++jj) vones[jj] = (short)0x3F80;  // bf16 1.0

  const int b = bh >> 4, h2 = bh & 15;

  for (int pass = 0; pass < 2; ++pass) {
    const int Qb = pass ? g : (7 - g);
    const int q0w = Qb * 256 + wid * 32;
    const int diag = q0w >> 6;       // wave's diagonal kv-tile
    const int ql0 = (wid & 1) * 32;  // q-local base within diag tile
    const int NTb = 4 * Qb + 4;      // pass trip count

    // Q as B-operand: col=q=lr, k=d
    short8 qf[2][2];
#pragma unroll
    for (int a = 0; a < 2; ++a)
#pragma unroll
      for (int kb = 0; kb < 2; ++kb)
        qf[a][kb] = *(const short8*)&Qh[(size_t)(q0w + a * 16 + lr) * D_ + kb * 32 + lk * 8];

    f32x4 o[2][4] = {};
    f32x4 lsum[2] = {};
    float mrun[2] = {-1e30f, -1e30f};

    stage(0);
    asm volatile("s_waitcnt vmcnt(0)" ::: "memory");
    __builtin_amdgcn_s_barrier();

    for (int t = 0; t < NTb; ++t) {
      if (t + 1 < NTb) stage(t + 1);  // other parity buffer: safe vs tile-t reads

      if (t <= diag) {
        char* kb_ = kvb[t & 1];
        char* vb_ = kvb[t & 1] + 8192;

        // K fragments from LDS (2-way conflict = free)
        short8 kf[2][4];
#pragma unroll
        for (int kb = 0; kb < 2; ++kb)
#pragma unroll
          for (int n = 0; n < 4; ++n)
            kf[kb][n] = *(const short8*)(kb_ + (n * 16 + lr) * 128 + ((kb * 64 + lk * 16) ^ rswz));

        // S^T = K Q^T
        f32x4 st[2][4] = {};
#pragma unroll
        for (int kb = 0; kb < 2; ++kb)
#pragma unroll
          for (int a = 0; a < 2; ++a)
#pragma unroll
            for (int n = 0; n < 4; ++n)
              st[a][n] = MFMA_BF16(kf[kb][n], qf[a][kb], st[a][n]);

        if (t == diag) {  // causal mask
#pragma unroll
          for (int a = 0; a < 2; ++a)
#pragma unroll
            for (int n = 0; n < 4; ++n)
#pragma unroll
              for (int r = 0; r < 4; ++r)
                if (n * 16 + lk * 4 + r > ql0 + a * 16 + lr) st[a][n][r] = -3e38f;
        }

        // row max (in-lane tree + 2 shuffles)
        float pm[2];
#pragma unroll
        for (int a = 0; a < 2; ++a) {
          float m0 = fmaxf(fmaxf(st[a][0][0], st[a][1][0]), fmaxf(st[a][2][0], st[a][3][0]));
          float m1 = fmaxf(fmaxf(st[a][0][1], st[a][1][1]), fmaxf(st[a][2][1], st[a][3][1]));
          float m2 = fmaxf(fmaxf(st[a][0][2], st[a][1][2]), fmaxf(st[a][2][2], st[a][3][2]));
          float m3 = fmaxf(fmaxf(st[a][0][3], st[a][1][3]), fmaxf(st[a][2][3], st[a][3][3]));
          float mx = fmaxf(fmaxf(m0, m1), fmaxf(m2, m3));
          mx = fmaxf(mx, __shfl_xor(mx, 16));
          mx = fmaxf(mx, __shfl_xor(mx, 32));
          pm[a] = mx * SC;
        }
        float need = fmaxf(pm[0] - mrun[0], pm[1] - mrun[1]);

        if (__any(need > 8.f)) {  // defer-max rescale (rare)
#pragma unroll
          for (int a = 0; a < 2; ++a) {
            float mnew = fmaxf(mrun[a], pm[a]);
            float sc = exp2f(mrun[a] - mnew);
            mrun[a] = mnew;
#pragma unroll
            for (int r = 0; r < 4; ++r) {
              float sco = __shfl(sc, (lane & 48) | (lk * 4 + r));
              lsum[a][r] *= sco;
#pragma unroll
              for (int nd = 0; nd < 4; ++nd) o[a][nd][r] *= sco;
            }
          }
        }

        // P = exp2(S*SC - m), packed bf16x4 -> per-wave LDS
#pragma unroll
        for (int a = 0; a < 2; ++a)
#pragma unroll
          for (int n = 0; n < 4; ++n) {
            float2 p01, p23;
            p01.x = exp2f(fmaf(st[a][n][0], SC, -mrun[a]));
            p01.y = exp2f(fmaf(st[a][n][1], SC, -mrun[a]));
            p23.x = exp2f(fmaf(st[a][n][2], SC, -mrun[a]));
            p23.y = exp2f(fmaf(st[a][n][3], SC, -mrun[a]));
            __hip_bfloat162 b01 = __float22bfloat162_rn(p01);
            __hip_bfloat162 b23 = __float22bfloat162_rn(p23);
            uint2 w;
            w.x = *(unsigned*)&b01;
            w.y = *(unsigned*)&b23;
            *(uint2*)(Pb + (a * 16 + lr) * 144 + n * 32 + lk * 8) = w;
          }

        // V fragments from LDS + in-tile PV (compiler waits P write->read)
        short8 vf[2][4];
#pragma unroll
        for (int kb = 0; kb < 2; ++kb)
#pragma unroll
          for (int nd = 0; nd < 4; ++nd)
            vf[kb][nd] = *(const short8*)(vb_ + (nd * 16 + lr) * 128 + ((kb * 64 + lk * 16) ^ rswz));
#pragma unroll
        for (int kb = 0; kb < 2; ++kb) {
          short8 pf0 = *(const short8*)(Pb + (0 + lr) * 144 + kb * 64 + lk * 16);
          short8 pf1 = *(const short8*)(Pb + (16 + lr) * 144 + kb * 64 + lk * 16);
#pragma unroll
          for (int nd = 0; nd < 4; ++nd) {
            o[0][nd] = MFMA_BF16(pf0, vf[kb][nd], o[0][nd]);
            o[1][nd] = MFMA_BF16(pf1, vf[kb][nd], o[1][nd]);
          }
          lsum[0] = MFMA_BF16(pf0, vones, lsum[0]);
          lsum[1] = MFMA_BF16(pf1, vones, lsum[1]);
        }
      }

      asm volatile("s_waitcnt vmcnt(0)" ::: "memory");  // stage(t+1) landed
      __builtin_amdgcn_s_barrier();
    }

#pragma unroll
    for (int a = 0; a < 2; ++a)
#pragma unroll
      for (int r = 0; r < 4; ++r) {
        float inv = 1.0f / lsum[a][r];
        int tq = q0w + a * 16 + lk * 4 + r;
#pragma unroll
        for (int nd = 0; nd < 4; ++nd)
          ctx[((size_t)b * T_ + tq) * E_ + h2 * D_ + nd * 16 + lr] = f2bf(o[a][nd][r] * inv);
      }
  }
}

// ---------------- launcher ----------------
extern "C" void kernel_launch(void* const* d_in, const int* in_sizes, int n_in,
                              void* d_out, int out_size, void* d_ws, size_t ws_size,
                              hipStream_t stream) {
  const float* x    = (const float*)d_in[0];
  const float* Wq   = (const float*)d_in[1];
  const float* Wk   = (const float*)d_in[2];
  const float* Wv   = (const float*)d_in[3];
  const float* Wout = (const float*)d_in[4];
  const float* bout = (const float*)d_in[5];
  float* out = (float*)d_out;

  const size_t MT = (size_t)B_ * T_;      // 8192
  const size_t XE = MT * E_;              // 8,388,608
  const size_t WE = (size_t)E_ * E_;      // 1,048,576

  size_t need = (XE * 5 + WE * 4) * sizeof(unsigned short);
  if (ws_size < need) return;

  unsigned short* xb  = (unsigned short*)d_ws;
  unsigned short* wqb = xb + XE;
  unsigned short* wkb = wqb + WE;
  unsigned short* wvb = wkb + WE;
  unsigned short* wob = wvb + WE;
  unsigned short* Qb  = wob + WE;
  unsigned short* Kb  = Qb + XE;
  unsigned short* VTb = Kb + XE;
  unsigned short* ctx = VTb + XE;

  cvt_all<<<6144, 256, 0, stream>>>(x, Wq, Wk, Wv, Wout, xb, wqb);

  gemm_qkv2<<<768, 512, 0, stream>>>(xb, wqb, wkb, wvb, Qb, Kb, VTb);

  attn_fused8<<<256, 512, 0, stream>>>(Qb, Kb, VTb, ctx);

  gemm_out2<<<256, 512, 0, stream>>>(ctx, wob, out, bout);
}

// Round 22
// 168.946 us; speedup vs baseline: 1.0853x; 1.0009x over previous
//
#include <hip/hip_runtime.h>
#include <hip/hip_bf16.h>
#include <stdint.h>
#include <math.h>

#define B_ 4
#define T_ 2048
#define E_ 1024
#define H_ 16
#define D_ 64

typedef __attribute__((ext_vector_type(8))) short short8;
typedef __attribute__((ext_vector_type(4))) short short4v;
typedef __attribute__((ext_vector_type(4))) float f32x4;

#define MFMA_BF16(a, b, c) __builtin_amdgcn_mfma_f32_16x16x32_bf16((a), (b), (c), 0, 0, 0)

__device__ __forceinline__ unsigned short f2bf(float f) {
  union { float f; unsigned u; } v; v.f = f;
  unsigned r = v.u + 0x7FFFu + ((v.u >> 16) & 1u);  // RNE
  return (unsigned short)(r >> 16);
}

#define GLOAD_LDS16(g, l)                                                        \
  __builtin_amdgcn_global_load_lds((const __attribute__((address_space(1))) void*)(g), \
                                   (__attribute__((address_space(3))) void*)(l), 16, 0, 0)

// ---------------- fp32 -> bf16 convert: x + 4 weights in ONE launch ----------
__global__ __launch_bounds__(256) void cvt_all(const float* __restrict__ x,
                                               const float* __restrict__ w0,
                                               const float* __restrict__ w1,
                                               const float* __restrict__ w2,
                                               const float* __restrict__ w3,
                                               unsigned short* __restrict__ xb,
                                               unsigned short* __restrict__ wb) {
  const int NX8 = 1048576;  // XE/8
  int i = blockIdx.x * blockDim.x + threadIdx.x;
  const float* src;
  unsigned short* dst;
  size_t off;
  if (i < NX8) {
    src = x; dst = xb; off = (size_t)i * 8;
  } else {
    int j = i - NX8;
    int which = j >> 17;             // WE/8 = 2^17
    int o = j & 131071;
    src = (which == 0) ? w0 : (which == 1) ? w1 : (which == 2) ? w2 : w3;
    dst = wb + ((size_t)which << 20);
    off = (size_t)o * 8;
  }
  const float4* p = (const float4*)(src + off);
  float4 a = p[0], b = p[1];
  short8 r;
  r[0] = (short)f2bf(a.x); r[1] = (short)f2bf(a.y);
  r[2] = (short)f2bf(a.z); r[3] = (short)f2bf(a.w);
  r[4] = (short)f2bf(b.x); r[5] = (short)f2bf(b.y);
  r[6] = (short)f2bf(b.z); r[7] = (short)f2bf(b.w);
  *(short8*)(dst + off) = r;
}

// =============== 128x256 2-phase pipelined GEMM template (r18, proven) =======
#define GEMM2_BODY(A_PTR, B_PTR)                                                  \
  const int K = E_;                                                               \
  const int NT = 16;                                                              \
  const int tid = threadIdx.x;                                                    \
  const int wid = tid >> 6;                                                       \
  const int lane = tid & 63;                                                      \
  const int lr = lane & 15;                                                       \
  const int lk = lane >> 4;                                                       \
  const int wm = wid >> 2, wn = wid & 3;                                          \
  const int srow = lane >> 3;                                                     \
  const int scol = ((lane & 7) ^ srow) * 8;                                       \
  const int rswz = (lr & 7) << 4;                                                 \
  const int kofs0 = (lk * 16) ^ rswz;                                             \
  const int kofs1 = (64 + lk * 16) ^ rswz;                                        \
  f32x4 acc[4][4] = {};                                                           \
  short8 af[4][2], bf0[2][2], bf1[2][2];                                          \
  auto stageA = [&](int tau) {                                                    \
    char* dst = lds + (tau & 1) * 49152 + wid * 1024;                             \
    const unsigned short* src = (A_PTR) + (size_t)(m0 + wid * 8 + srow) * K +     \
                                tau * 64 + scol;                                  \
    GLOAD_LDS16(src, dst);                                                        \
    GLOAD_LDS16(src + (size_t)64 * K, dst + 8192);                                \
  };                                                                              \
  auto stageB = [&](int tau) {                                                    \
    char* dst = lds + (tau & 1) * 49152 + 16384 + wid * 1024;                     \
    const unsigned short* src = (B_PTR) + (size_t)(n0 + wid * 8 + srow) * K +     \
                                tau * 64 + scol;                                  \
    GLOAD_LDS16(src, dst);                                                        \
    GLOAD_LDS16(src + (size_t)64 * K, dst + 8192);                                \
    GLOAD_LDS16(src + (size_t)128 * K, dst + 16384);                              \
    GLOAD_LDS16(src + (size_t)192 * K, dst + 24576);                              \
  };                                                                              \
  stageB(0); stageA(0); stageB(1);                                                \
  asm volatile("s_waitcnt vmcnt(4)" ::: "memory");                                \
  __builtin_amdgcn_s_barrier();                                                   \
  for (int t = 0; t < NT; ++t) {                                                  \
    char* bufA = lds + (t & 1) * 49152;                                           \
    char* bufB = bufA + 16384;                                                    \
    _Pragma("unroll")                                                             \
    for (int i = 0; i < 4; ++i) {                                                 \
      int row = wm * 64 + i * 16 + lr;                                            \
      af[i][0] = *(const short8*)(bufA + row * 128 + kofs0);                      \
      af[i][1] = *(const short8*)(bufA + row * 128 + kofs1);                      \
    }                                                                             \
    _Pragma("unroll")                                                             \
    for (int i = 0; i < 2; ++i) {                                                 \
      int row0 = wn * 64 + i * 16 + lr;                                           \
      int row1 = wn * 64 + (2 + i) * 16 + lr;                                     \
      bf0[i][0] = *(const short8*)(bufB + row0 * 128 + kofs0);                    \
      bf0[i][1] = *(const short8*)(bufB + row0 * 128 + kofs1);                    \
      bf1[i][0] = *(const short8*)(bufB + row1 * 128 + kofs0);                    \
      bf1[i][1] = *(const short8*)(bufB + row1 * 128 + kofs1);                    \
    }                                                                             \
    if (t + 1 < NT) stageA(t + 1);                                                \
    __builtin_amdgcn_s_barrier();                                                 \
    asm volatile("s_waitcnt lgkmcnt(0)" ::: "memory");                            \
    __builtin_amdgcn_sched_barrier(0);                                            \
    __builtin_amdgcn_s_setprio(1);                                                \
    _Pragma("unroll")                                                             \
    for (int i = 0; i < 4; ++i)                                                   \
      _Pragma("unroll")                                                           \
      for (int jn = 0; jn < 2; ++jn) {                                            \
        acc[i][jn] = MFMA_BF16(af[i][0], bf0[jn][0], acc[i][jn]);                 \
        acc[i][jn] = MFMA_BF16(af[i][1], bf0[jn][1], acc[i][jn]);                 \
      }                                                                           \
    __builtin_amdgcn_s_setprio(0);                                                \
    __builtin_amdgcn_s_barrier();                                                 \
    if (t + 2 < NT) stageB(t + 2);                                                \
    __builtin_amdgcn_s_setprio(1);                                                \
    _Pragma("unroll")                                                             \
    for (int i = 0; i < 4; ++i)                                                   \
      _Pragma("unroll")                                                           \
      for (int jn = 0; jn < 2; ++jn) {                                            \
        acc[i][2 + jn] = MFMA_BF16(af[i][0], bf1[jn][0], acc[i][2 + jn]);         \
        acc[i][2 + jn] = MFMA_BF16(af[i][1], bf1[jn][1], acc[i][2 + jn]);         \
      }                                                                           \
    __builtin_amdgcn_s_setprio(0);                                                \
    if (t < NT - 2) asm volatile("s_waitcnt vmcnt(4)" ::: "memory");              \
    else            asm volatile("s_waitcnt vmcnt(0)" ::: "memory");              \
    __builtin_amdgcn_s_barrier();                                                 \
  }

// ---------------- QKV GEMM (768 blocks = 3 exact rounds at 1 blk/CU) ---------
__global__ __launch_bounds__(512) void gemm_qkv2(const unsigned short* __restrict__ A,
                                                 const unsigned short* __restrict__ Wq,
                                                 const unsigned short* __restrict__ Wk,
                                                 const unsigned short* __restrict__ Wv,
                                                 unsigned short* __restrict__ Qo,
                                                 unsigned short* __restrict__ Ko,
                                                 unsigned short* __restrict__ Vo) {
  __shared__ __align__(16) char lds[98304];
  const int bid = blockIdx.x;
  const int xcd = bid & 7;
  const int p = bid >> 3;               // 0..95
  const int m0 = (xcd * 8 + (p & 7)) * 128;
  const int j = p >> 3;                 // 0..11
  const int n0 = (j & 3) * 256;
  const int sel = j >> 2;
  const unsigned short* Bm = (sel == 0) ? Wq : (sel == 1) ? Wk : Wv;

  GEMM2_BODY(A, Bm)

  unsigned short* outp = (sel == 0) ? Qo : (sel == 1) ? Ko : Vo;
#pragma unroll
  for (int mi = 0; mi < 4; ++mi)
#pragma unroll
    for (int ni = 0; ni < 4; ++ni) {
      int row0 = m0 + wm * 64 + mi * 16 + lk * 4;
      int col = n0 + wn * 64 + ni * 16 + lr;
      int b = row0 >> 11, t0 = row0 & (T_ - 1), h = col >> 6, d = col & (D_ - 1);
      if (sel == 2) {
        short4v vv;
#pragma unroll
        for (int r = 0; r < 4; ++r) vv[r] = (short)f2bf(acc[mi][ni][r]);
        *(short4v*)&outp[(((size_t)(b * H_ + h)) * D_ + d) * T_ + t0] = vv;  // [BH][D][T]
      } else {
#pragma unroll
        for (int r = 0; r < 4; ++r)
          outp[(((size_t)(b * H_ + h)) * T_ + t0 + r) * D_ + d] = f2bf(acc[mi][ni][r]);
      }
    }
}

// ---------------- out-proj GEMM (256 blocks = exactly 1/CU) ------------------
__global__ __launch_bounds__(512) void gemm_out2(const unsigned short* __restrict__ A,
                                                 const unsigned short* __restrict__ Wout,
                                                 float* __restrict__ outp,
                                                 const float* __restrict__ bias) {
  __shared__ __align__(16) char lds[98304];
  const int bid = blockIdx.x;
  const int xcd = bid & 7;
  const int p = bid >> 3;               // 0..31
  const int m0 = (xcd * 8 + (p & 7)) * 128;
  const int n0 = (p >> 3) * 256;

  GEMM2_BODY(A, Wout)

#pragma unroll
  for (int mi = 0; mi < 4; ++mi)
#pragma unroll
    for (int ni = 0; ni < 4; ++ni) {
      int row0 = m0 + wm * 64 + mi * 16 + lk * 4;
      int col = n0 + wn * 64 + ni * 16 + lr;
      float bv = bias[col];
#pragma unroll
      for (int r = 0; r < 4; ++r)
        outp[(size_t)(row0 + r) * E_ + col] = acc[mi][ni][r] + bv;
    }
}

// ---------------- fused causal flash attention (8-wave, zero-LDS-P) ----------
// 256 blocks x 512 thr = 1 block/CU, intrinsic pairing (q-blocks 7-g then g:
// exactly 36 tiles/block). K/V staged in LDS (32KB, double-buffered, GEMM
// swizzle). P never touches LDS: sigma k-slot packing in registers (r6 math,
// proven) + sigma-ordered V reads as 2x ds_read_b64 per fragment — removes
// the 96KB/tile P round-trip that bound r19-r21 at ~94us.
__global__ __launch_bounds__(512) void attn_fused8(const unsigned short* __restrict__ Q,
                                                   const unsigned short* __restrict__ K,
                                                   const unsigned short* __restrict__ VT,
                                                   unsigned short* __restrict__ ctx) {
  __shared__ __align__(16) char kvb[2][16384];  // [buf][K 8K | V 8K]
  const int tid = threadIdx.x;
  const int wid = tid >> 6;
  const int lane = tid & 63;
  const int lr = lane & 15;
  const int lk = lane >> 4;

  // 256 = 8 xcd x 8 heads x 4 pair-ids
  const int bid = blockIdx.x;
  const int xcd = bid & 7;
  const int p = bid >> 3;            // 0..31
  const int bh = xcd * 8 + (p & 7);
  const int g = p >> 3;              // 0..3

  const unsigned short* Qh = Q + (size_t)bh * T_ * D_;
  const unsigned short* Kh = K + (size_t)bh * T_ * D_;
  const unsigned short* Vh = VT + (size_t)bh * T_ * D_;  // [D][T]

  const float SC = 0.125f * 1.44269504089f;  // 1/sqrt(D) * log2(e)

  // staging: thread stages one 16B chunk of K and one of V per tile
  const int srow = tid >> 3;                       // 0..63
  const int scol = ((tid & 7) ^ (srow & 7)) * 8;   // pre-swizzled col (elems)
  const int rswz = (lr & 7) << 4;                  // read-side XOR (bytes)

  auto stage = [&](int t) {
    char* dst = kvb[t & 1] + tid * 16;
    GLOAD_LDS16(Kh + (size_t)(t * 64 + srow) * D_ + scol, dst);
    GLOAD_LDS16(Vh + (size_t)srow * T_ + t * 64 + scol, dst + 8192);
  };

  short8 vones;
#pragma unroll
  for (int jj = 0; jj < 8; ++jj) vones[jj] = (short)0x3F80;  // bf16 1.0

  const int b = bh >> 4, h2 = bh & 15;

  for (int pass = 0; pass < 2; ++pass) {
    const int Qb = pass ? g : (7 - g);
    const int q0w = Qb * 256 + wid * 32;
    const int diag = q0w >> 6;       // wave's diagonal kv-tile
    const int ql0 = (wid & 1) * 32;  // q-local base within diag tile
    const int NTb = 4 * Qb + 4;      // pass trip count

    // Q as B-operand: col=q=lr, k=d
    short8 qf[2][2];
#pragma unroll
    for (int a = 0; a < 2; ++a)
#pragma unroll
      for (int kb = 0; kb < 2; ++kb)
        qf[a][kb] = *(const short8*)&Qh[(size_t)(q0w + a * 16 + lr) * D_ + kb * 32 + lk * 8];

    f32x4 o[2][4] = {};
    f32x4 lsum[2] = {};
    float mrun[2] = {-1e30f, -1e30f};

    stage(0);
    asm volatile("s_waitcnt vmcnt(0)" ::: "memory");
    __builtin_amdgcn_s_barrier();

    for (int t = 0; t < NTb; ++t) {
      if (t + 1 < NTb) stage(t + 1);  // other parity buffer: safe vs tile-t reads

      if (t <= diag) {
        char* kb_ = kvb[t & 1];
        char* vb_ = kvb[t & 1] + 8192;

        // K fragments from LDS (2-way conflict = free)
        short8 kf[2][4];
#pragma unroll
        for (int kb = 0; kb < 2; ++kb)
#pragma unroll
          for (int n = 0; n < 4; ++n)
            kf[kb][n] = *(const short8*)(kb_ + (n * 16 + lr) * 128 + ((kb * 64 + lk * 16) ^ rswz));

        // V fragments with sigma k-slot layout: slot j<4 -> kv=32h+lk*4+j,
        // slot j>=4 -> kv=32h+16+lk*4+(j-4). Two b64 LDS reads per fragment.
        short8 vreg[2][4];
#pragma unroll
        for (int h = 0; h < 2; ++h)
#pragma unroll
          for (int nd = 0; nd < 4; ++nd) {
            const char* vrow = vb_ + (nd * 16 + lr) * 128;
            *(uint2*)&vreg[h][nd] = *(const uint2*)(vrow + ((h * 64 + lk * 8) ^ rswz));
            *((uint2*)&vreg[h][nd] + 1) = *(const uint2*)(vrow + ((h * 64 + 32 + lk * 8) ^ rswz));
          }

        // S^T = K Q^T
        f32x4 st[2][4] = {};
#pragma unroll
        for (int kb = 0; kb < 2; ++kb)
#pragma unroll
          for (int a = 0; a < 2; ++a)
#pragma unroll
            for (int n = 0; n < 4; ++n)
              st[a][n] = MFMA_BF16(kf[kb][n], qf[a][kb], st[a][n]);

        if (t == diag) {  // causal mask
#pragma unroll
          for (int a = 0; a < 2; ++a)
#pragma unroll
            for (int n = 0; n < 4; ++n)
#pragma unroll
              for (int r = 0; r < 4; ++r)
                if (n * 16 + lk * 4 + r > ql0 + a * 16 + lr) st[a][n][r] = -3e38f;
        }

        // row max (in-lane tree + 2 shuffles)
        float pm[2];
#pragma unroll
        for (int a = 0; a < 2; ++a) {
          float m0 = fmaxf(fmaxf(st[a][0][0], st[a][1][0]), fmaxf(st[a][2][0], st[a][3][0]));
          float m1 = fmaxf(fmaxf(st[a][0][1], st[a][1][1]), fmaxf(st[a][2][1], st[a][3][1]));
          float m2 = fmaxf(fmaxf(st[a][0][2], st[a][1][2]), fmaxf(st[a][2][2], st[a][3][2]));
          float m3 = fmaxf(fmaxf(st[a][0][3], st[a][1][3]), fmaxf(st[a][2][3], st[a][3][3]));
          float mx = fmaxf(fmaxf(m0, m1), fmaxf(m2, m3));
          mx = fmaxf(mx, __shfl_xor(mx, 16));
          mx = fmaxf(mx, __shfl_xor(mx, 32));
          pm[a] = mx * SC;
        }
        float need = fmaxf(pm[0] - mrun[0], pm[1] - mrun[1]);

        if (__any(need > 8.f)) {  // defer-max rescale (rare)
#pragma unroll
          for (int a = 0; a < 2; ++a) {
            float mnew = fmaxf(mrun[a], pm[a]);
            float sc = exp2f(mrun[a] - mnew);
            mrun[a] = mnew;
#pragma unroll
            for (int r = 0; r < 4; ++r) {
              float sco = __shfl(sc, (lane & 48) | (lk * 4 + r));
              lsum[a][r] *= sco;
#pragma unroll
              for (int nd = 0; nd < 4; ++nd) o[a][nd][r] *= sco;
            }
          }
        }

        // P = exp2(S*SC - m): pack in-register to sigma A-fragments (no LDS)
        short8 pf[2][2];
#pragma unroll
        for (int a = 0; a < 2; ++a) {
          f32x4 pt[4];
#pragma unroll
          for (int n = 0; n < 4; ++n)
#pragma unroll
            for (int r = 0; r < 4; ++r)
              pt[n][r] = exp2f(fmaf(st[a][n][r], SC, -mrun[a]));
#pragma unroll
          for (int h = 0; h < 2; ++h) {
            float2 x01, x23, y01, y23;
            x01.x = pt[2 * h][0];     x01.y = pt[2 * h][1];
            x23.x = pt[2 * h][2];     x23.y = pt[2 * h][3];
            y01.x = pt[2 * h + 1][0]; y01.y = pt[2 * h + 1][1];
            y23.x = pt[2 * h + 1][2]; y23.y = pt[2 * h + 1][3];
            __hip_bfloat162 b0 = __float22bfloat162_rn(x01);
            __hip_bfloat162 b1 = __float22bfloat162_rn(x23);
            __hip_bfloat162 b2 = __float22bfloat162_rn(y01);
            __hip_bfloat162 b3 = __float22bfloat162_rn(y23);
            unsigned* w = (unsigned*)&pf[a][h];
            w[0] = *(unsigned*)&b0;
            w[1] = *(unsigned*)&b1;
            w[2] = *(unsigned*)&b2;
            w[3] = *(unsigned*)&b3;
          }
        }

        // O += P V ; lsum += P * ones  (pure register MFMA)
#pragma unroll
        for (int h = 0; h < 2; ++h) {
#pragma unroll
          for (int nd = 0; nd < 4; ++nd) {
            o[0][nd] = MFMA_BF16(pf[0][h], vreg[h][nd], o[0][nd]);
            o[1][nd] = MFMA_BF16(pf[1][h], vreg[h][nd], o[1][nd]);
          }
          lsum[0] = MFMA_BF16(pf[0][h], vones, lsum[0]);
          lsum[1] = MFMA_BF16(pf[1][h], vones, lsum[1]);
        }
      }

      asm volatile("s_waitcnt vmcnt(0)" ::: "memory");  // stage(t+1) landed
      __builtin_amdgcn_s_barrier();
    }

#pragma unroll
    for (int a = 0; a < 2; ++a)
#pragma unroll
      for (int r = 0; r < 4; ++r) {
        float inv = 1.0f / lsum[a][r];
        int tq = q0w + a * 16 + lk * 4 + r;
#pragma unroll
        for (int nd = 0; nd < 4; ++nd)
          ctx[((size_t)b * T_ + tq) * E_ + h2 * D_ + nd * 16 + lr] = f2bf(o[a][nd][r] * inv);
      }
  }
}

// ---------------- launcher ----------------
extern "C" void kernel_launch(void* const* d_in, const int* in_sizes, int n_in,
                              void* d_out, int out_size, void* d_ws, size_t ws_size,
                              hipStream_t stream) {
  const float* x    = (const float*)d_in[0];
  const float* Wq   = (const float*)d_in[1];
  const float* Wk   = (const float*)d_in[2];
  const float* Wv   = (const float*)d_in[3];
  const float* Wout = (const float*)d_in[4];
  const float* bout = (const float*)d_in[5];
  float* out = (float*)d_out;

  const size_t MT = (size_t)B_ * T_;      // 8192
  const size_t XE = MT * E_;              // 8,388,608
  const size_t WE = (size_t)E_ * E_;      // 1,048,576

  size_t need = (XE * 5 + WE * 4) * sizeof(unsigned short);
  if (ws_size < need) return;

  unsigned short* xb  = (unsigned short*)d_ws;
  unsigned short* wqb = xb + XE;
  unsigned short* wkb = wqb + WE;
  unsigned short* wvb = wkb + WE;
  unsigned short* wob = wvb + WE;
  unsigned short* Qb  = wob + WE;
  unsigned short* Kb  = Qb + XE;
  unsigned short* VTb = Kb + XE;
  unsigned short* ctx = VTb + XE;

  cvt_all<<<6144, 256, 0, stream>>>(x, Wq, Wk, Wv, Wout, xb, wqb);

  gemm_qkv2<<<768, 512, 0, stream>>>(xb, wqb, wkb, wvb, Qb, Kb, VTb);

  attn_fused8<<<256, 512, 0, stream>>>(Qb, Kb, VTb, ctx);

  gemm_out2<<<256, 512, 0, stream>>>(ctx, wob, out, bout);
}